// Round 1
// baseline (3042.531 us; speedup 1.0000x reference)
//
#include <hip/hip_runtime.h>
#include <hip/hip_bf16.h>

// Problem: out[b,t,k,f] = sum_d x[b,t,d] * (qw[k,d,f]-qz[k,d/128,f])*sc[k,d/128,f]
// GEMM view: C[M=8192][N=16384] = A[M][D=4096] * W[D][N], N = k*F+f.

#define BM 128
#define BN 128
#define BK 64
#define LDP 72   // padded LDS inner dim (144B rows: 16B-aligned, ~2-way conflicts)

typedef __attribute__((ext_vector_type(8))) short bf16x8;
typedef __attribute__((ext_vector_type(4))) float f32x4;

static constexpr int Bsz = 4, Tt = 2048, Dd = 4096, Kk = 2, Ff = 8192, Gg = 32;
static constexpr int M    = Bsz * Tt;   // 8192
static constexpr int NTOT = Kk * Ff;    // 16384
static constexpr int NM   = M / BM;     // 64 m-tiles
static constexpr int NN   = NTOT / BN;  // 128 n-tiles

__device__ __forceinline__ short f2bf(float f) {
    __hip_bfloat16 h = __float2bfloat16(f);
    return *reinterpret_cast<short*>(&h);
}

__global__ __launch_bounds__(256) void int4_gemm(
    const float* __restrict__ x,
    const int*   __restrict__ qw,
    const int*   __restrict__ qz,
    const float* __restrict__ sc,
    float*       __restrict__ out)
{
    __shared__ short As[BM][LDP];  // [m][d]  bf16 bits
    __shared__ short Bs[BN][LDP];  // [f][d]  bf16 bits (transposed weight tile)

    const int t = threadIdx.x;

    // XCD-aware swizzle: each XCD gets a contiguous 1024-block chunk (8192 % 8 == 0)
    int gid = (blockIdx.x & 7) * (NM * NN / 8) + (blockIdx.x >> 3);
    // n-major: consecutive gid share the same weight n-panel (L2 reuse)
    const int bm = gid & (NM - 1);
    const int bn = gid >> 6;            // log2(NM)=6
    const int kse = bn >> 6;            // F/BN = 64 n-tiles per k
    const int f0  = (bn & 63) * BN;
    const int m0  = bm * BM;

    const int wave = t >> 6, lane = t & 63;
    const int wm = wave >> 1, wn = wave & 1;   // 2x2 waves, each 64x64 output
    const int l15 = lane & 15, lhi = lane >> 4;

    // A staging: 16 threads/row (float4 along d), 16 rows/pass, 8 passes
    const int am = t >> 4;
    const int ad = (t & 15) * 4;
    // B staging: 128 threads across f, 2 groups of 4 d-rows, 8 passes
    const int bf = t & 127;
    const int bd = (t >> 7) * 4;

    const int*   qwk = qw + (size_t)kse * Dd * Ff;
    const int*   qzk = qz + (size_t)kse * Gg * Ff;
    const float* sck = sc + (size_t)kse * Gg * Ff;

    f32x4 acc[4][4] = {};

    for (int d0 = 0; d0 < Dd; d0 += BK) {
        __syncthreads();

        // ---- stage A: x[m0..+128][d0..+64] fp32 -> bf16 LDS ----
        #pragma unroll
        for (int p = 0; p < 8; ++p) {
            int m = p * 16 + am;
            const float4 v = *reinterpret_cast<const float4*>(
                &x[(size_t)(m0 + m) * Dd + d0 + ad]);
            short4 wv;
            wv.x = f2bf(v.x); wv.y = f2bf(v.y); wv.z = f2bf(v.z); wv.w = f2bf(v.w);
            *reinterpret_cast<short4*>(&As[m][ad]) = wv;
        }

        // ---- stage B: dequant qw[d0..+64][f0..+128] -> bf16 LDS (transposed) ----
        {
            const int g = d0 >> 7;  // quant group constant over this K-step
            const int   zv = qzk[g * Ff + f0 + bf];
            const float sv = sck[g * Ff + f0 + bf];
            #pragma unroll
            for (int p = 0; p < 8; ++p) {
                int dl = p * 8 + bd;
                const int* qp = qwk + (size_t)(d0 + dl) * Ff + f0 + bf;
                short4 wv;
                wv.x = f2bf((float)(qp[0]        - zv) * sv);
                wv.y = f2bf((float)(qp[Ff]       - zv) * sv);
                wv.z = f2bf((float)(qp[2 * Ff]   - zv) * sv);
                wv.w = f2bf((float)(qp[3 * Ff]   - zv) * sv);
                *reinterpret_cast<short4*>(&Bs[bf][dl]) = wv;
            }
        }

        __syncthreads();

        // ---- MFMA: 2 k-slices of 32, 4x4 fragments per wave ----
        #pragma unroll
        for (int kk = 0; kk < BK; kk += 32) {
            bf16x8 af[4], bb[4];
            #pragma unroll
            for (int i = 0; i < 4; ++i)
                af[i] = *reinterpret_cast<const bf16x8*>(
                    &As[wm * 64 + i * 16 + l15][kk + lhi * 8]);
            #pragma unroll
            for (int i = 0; i < 4; ++i)
                bb[i] = *reinterpret_cast<const bf16x8*>(
                    &Bs[wn * 64 + i * 16 + l15][kk + lhi * 8]);
            #pragma unroll
            for (int mi = 0; mi < 4; ++mi)
                #pragma unroll
                for (int ni = 0; ni < 4; ++ni)
                    acc[mi][ni] = __builtin_amdgcn_mfma_f32_16x16x32_bf16(
                        af[mi], bb[ni], acc[mi][ni], 0, 0, 0);
        }
    }

    // ---- epilogue: C/D layout col=lane&15, row=(lane>>4)*4+reg ----
    const int crow0 = m0 + wm * 64 + lhi * 4;
    const int ccol0 = bn * BN + wn * 64 + l15;
    #pragma unroll
    for (int mi = 0; mi < 4; ++mi)
        #pragma unroll
        for (int ni = 0; ni < 4; ++ni)
            #pragma unroll
            for (int r = 0; r < 4; ++r)
                out[(size_t)(crow0 + mi * 16 + r) * NTOT + ccol0 + ni * 16] =
                    acc[mi][ni][r];
}

extern "C" void kernel_launch(void* const* d_in, const int* in_sizes, int n_in,
                              void* d_out, int out_size, void* d_ws, size_t ws_size,
                              hipStream_t stream) {
    const float* x  = (const float*)d_in[0];
    const int*   qw = (const int*)d_in[1];
    const int*   qz = (const int*)d_in[2];
    const float* sc = (const float*)d_in[3];
    float*       out = (float*)d_out;

    hipLaunchKernelGGL(int4_gemm, dim3(NM * NN), dim3(256), 0, stream,
                       x, qw, qz, sc, out);
}

// Round 2
// 1974.598 us; speedup vs baseline: 1.5408x; 1.5408x over previous
//
#include <hip/hip_runtime.h>
#include <hip/hip_bf16.h>
#include <stdint.h>

// out[b,t,k,f] = sum_d x[b,t,d] * (qw[k,d,f]-qz[k,d/128,f])*sc[k,d/128,f]
// Stage 1: x fp32 -> bf16 Xb[M][D]; qw int4 -> bf16 Wt[N][D] (transposed), both in d_ws.
// Stage 2: m97-structure 128x128x64 bf16 MFMA GEMM with global_load_lds staging.

typedef __attribute__((ext_vector_type(8))) short bf16x8;
typedef __attribute__((ext_vector_type(4))) float f32x4;

static constexpr int Bsz = 4, Tt = 2048, Dd = 4096, Kk = 2, Ff = 8192, Gg = 32;
static constexpr int M    = Bsz * Tt;   // 8192
static constexpr int NTOT = Kk * Ff;    // 16384
static constexpr int BM = 128, BN = 128, BK = 64;
static constexpr int NM = M / BM;       // 64
static constexpr int NN = NTOT / BN;    // 128

__device__ __forceinline__ short f2bf(float f) {
    __hip_bfloat16 h = __float2bfloat16(f);
    return *reinterpret_cast<short*>(&h);
}

// ---------------- Stage 1a: x fp32 -> bf16 ----------------
__global__ __launch_bounds__(256) void xcvt(const float* __restrict__ x,
                                            short* __restrict__ xb) {
    const size_t n4 = (size_t)M * Dd / 4;
    const size_t stride = (size_t)gridDim.x * blockDim.x;
    for (size_t i = (size_t)blockIdx.x * blockDim.x + threadIdx.x; i < n4; i += stride) {
        float4 v = reinterpret_cast<const float4*>(x)[i];
        short4 o;
        o.x = f2bf(v.x); o.y = f2bf(v.y); o.z = f2bf(v.z); o.w = f2bf(v.w);
        reinterpret_cast<short4*>(xb)[i] = o;
    }
}

// ---------------- Stage 1b: dequant + transpose: Wt[k*F+f][d] ----------------
__global__ __launch_bounds__(256) void wdq(const int* __restrict__ qw,
                                           const int* __restrict__ qz,
                                           const float* __restrict__ sc,
                                           short* __restrict__ wt) {
    __shared__ short tile[64][72];  // padded: transpose staging
    const int b = blockIdx.x;
    const int k   = b >> 13;        // 8192 blocks per k
    const int rem = b & 8191;
    const int d0 = (rem >> 7) << 6; // 64 consecutive d (within one 128-group)
    const int f0 = (rem & 127) << 6;
    const int t = threadIdx.x;
    const int g = d0 >> 7;
    const int fi = (t & 15) * 4;

    const int4   z4 = *reinterpret_cast<const int4*>(&qz[((size_t)k * Gg + g) * Ff + f0 + fi]);
    const float4 s4 = *reinterpret_cast<const float4*>(&sc[((size_t)k * Gg + g) * Ff + f0 + fi]);

    #pragma unroll
    for (int p = 0; p < 4; ++p) {
        const int dl = p * 16 + (t >> 4);
        const int4 qv = *reinterpret_cast<const int4*>(
            &qw[((size_t)k * Dd + d0 + dl) * Ff + f0 + fi]);
        tile[fi + 0][dl] = f2bf((float)(qv.x - z4.x) * s4.x);
        tile[fi + 1][dl] = f2bf((float)(qv.y - z4.y) * s4.y);
        tile[fi + 2][dl] = f2bf((float)(qv.z - z4.z) * s4.z);
        tile[fi + 3][dl] = f2bf((float)(qv.w - z4.w) * s4.w);
    }
    __syncthreads();

    const int fl  = t >> 2;
    const int dsg = (t & 3) * 16;
    bf16x8 v0 = *reinterpret_cast<const bf16x8*>(&tile[fl][dsg]);
    bf16x8 v1 = *reinterpret_cast<const bf16x8*>(&tile[fl][dsg + 8]);
    short* dst = wt + ((size_t)(k * Ff + f0 + fl)) * Dd + d0 + dsg;
    *reinterpret_cast<bf16x8*>(dst)     = v0;
    *reinterpret_cast<bf16x8*>(dst + 8) = v1;
}

// ---------------- Stage 2: bf16 GEMM (m97 structure) ----------------
__global__ __launch_bounds__(256) void gemm_bf16(const short* __restrict__ A,   // [M][Dd]
                                                 const short* __restrict__ Bt,  // [NTOT][Dd]
                                                 float* __restrict__ out) {
    __shared__ short As[BM * BK];
    __shared__ short Bs[BN * BK];
    const int t = threadIdx.x;
    const int wave = t >> 6, lane = t & 63;

    // bijective XCD swizzle (8192 % 8 == 0), n-major for B-panel L2 reuse
    const int swz = (blockIdx.x & 7) * (NM * NN / 8) + (blockIdx.x >> 3);
    const int bm = swz & (NM - 1);
    const int bn = swz >> 6;
    const int m0 = bm * BM, n0 = bn * BN;
    const int wm = wave >> 1, wn = wave & 1;
    const int l15 = lane & 15, lhi = lane >> 4;

    // global_load_lds: wave-uniform LDS base + lane*16B; lane l covers
    // row base_row + l/8, bf16 cols (l%8)*8 .. +8
    const short* aG = A  + (size_t)(m0 + wave * 32 + (lane >> 3)) * Dd + (lane & 7) * 8;
    const short* bG = Bt + (size_t)(n0 + wave * 32 + (lane >> 3)) * Dd + (lane & 7) * 8;
    short* aL = &As[(wave * 32) * BK];
    short* bL = &Bs[(wave * 32) * BK];

    f32x4 acc[4][4] = {};

    for (int d0 = 0; d0 < Dd; d0 += BK) {
        #pragma unroll
        for (int i = 0; i < 4; ++i)
            __builtin_amdgcn_global_load_lds(
                (const __attribute__((address_space(1))) void*)(aG + (size_t)i * 8 * Dd + d0),
                (__attribute__((address_space(3))) void*)(aL + i * 8 * BK), 16, 0, 0);
        #pragma unroll
        for (int i = 0; i < 4; ++i)
            __builtin_amdgcn_global_load_lds(
                (const __attribute__((address_space(1))) void*)(bG + (size_t)i * 8 * Dd + d0),
                (__attribute__((address_space(3))) void*)(bL + i * 8 * BK), 16, 0, 0);
        __syncthreads();  // drains vmcnt -> LDS tile ready

        #pragma unroll
        for (int kk = 0; kk < BK; kk += 32) {
            bf16x8 af[4], bb[4];
            #pragma unroll
            for (int i = 0; i < 4; ++i)
                af[i] = *reinterpret_cast<const bf16x8*>(
                    &As[(wm * 64 + i * 16 + l15) * BK + kk + lhi * 8]);
            #pragma unroll
            for (int i = 0; i < 4; ++i)
                bb[i] = *reinterpret_cast<const bf16x8*>(
                    &Bs[(wn * 64 + i * 16 + l15) * BK + kk + lhi * 8]);
            #pragma unroll
            for (int mi = 0; mi < 4; ++mi)
                #pragma unroll
                for (int ni = 0; ni < 4; ++ni)
                    acc[mi][ni] = __builtin_amdgcn_mfma_f32_16x16x32_bf16(
                        af[mi], bb[ni], acc[mi][ni], 0, 0, 0);
        }
        __syncthreads();  // all reads done before next overwrite
    }

    const int crow0 = m0 + wm * 64 + lhi * 4;
    const int ccol0 = n0 + wn * 64 + l15;
    #pragma unroll
    for (int mi = 0; mi < 4; ++mi)
        #pragma unroll
        for (int ni = 0; ni < 4; ++ni)
            #pragma unroll
            for (int r = 0; r < 4; ++r)
                out[(size_t)(crow0 + mi * 16 + r) * NTOT + ccol0 + ni * 16] =
                    acc[mi][ni][r];
}

// ---------------- Fallback: round-1 fused kernel (if ws too small) ----------------
#define LDP 72
__global__ __launch_bounds__(256) void int4_gemm(
    const float* __restrict__ x,
    const int*   __restrict__ qw,
    const int*   __restrict__ qz,
    const float* __restrict__ sc,
    float*       __restrict__ out)
{
    __shared__ short As[BM][LDP];
    __shared__ short Bs[BN][LDP];
    const int t = threadIdx.x;
    int gid = (blockIdx.x & 7) * (NM * NN / 8) + (blockIdx.x >> 3);
    const int bm = gid & (NM - 1);
    const int bn = gid >> 6;
    const int kse = bn >> 6;
    const int f0  = (bn & 63) * BN;
    const int m0  = bm * BM;
    const int wave = t >> 6, lane = t & 63;
    const int wm = wave >> 1, wn = wave & 1;
    const int l15 = lane & 15, lhi = lane >> 4;
    const int am = t >> 4;
    const int ad = (t & 15) * 4;
    const int bf = t & 127;
    const int bd = (t >> 7) * 4;
    const int*   qwk = qw + (size_t)kse * Dd * Ff;
    const int*   qzk = qz + (size_t)kse * Gg * Ff;
    const float* sck = sc + (size_t)kse * Gg * Ff;
    f32x4 acc[4][4] = {};
    for (int d0 = 0; d0 < Dd; d0 += BK) {
        __syncthreads();
        #pragma unroll
        for (int p = 0; p < 8; ++p) {
            int m = p * 16 + am;
            const float4 v = *reinterpret_cast<const float4*>(
                &x[(size_t)(m0 + m) * Dd + d0 + ad]);
            short4 wv;
            wv.x = f2bf(v.x); wv.y = f2bf(v.y); wv.z = f2bf(v.z); wv.w = f2bf(v.w);
            *reinterpret_cast<short4*>(&As[m][ad]) = wv;
        }
        {
            const int g = d0 >> 7;
            const int   zv = qzk[g * Ff + f0 + bf];
            const float sv = sck[g * Ff + f0 + bf];
            #pragma unroll
            for (int p = 0; p < 8; ++p) {
                int dl = p * 8 + bd;
                const int* qp = qwk + (size_t)(d0 + dl) * Ff + f0 + bf;
                short4 wv;
                wv.x = f2bf((float)(qp[0]      - zv) * sv);
                wv.y = f2bf((float)(qp[Ff]     - zv) * sv);
                wv.z = f2bf((float)(qp[2 * Ff] - zv) * sv);
                wv.w = f2bf((float)(qp[3 * Ff] - zv) * sv);
                *reinterpret_cast<short4*>(&Bs[bf][dl]) = wv;
            }
        }
        __syncthreads();
        #pragma unroll
        for (int kk = 0; kk < BK; kk += 32) {
            bf16x8 af[4], bb[4];
            #pragma unroll
            for (int i = 0; i < 4; ++i)
                af[i] = *reinterpret_cast<const bf16x8*>(
                    &As[wm * 64 + i * 16 + l15][kk + lhi * 8]);
            #pragma unroll
            for (int i = 0; i < 4; ++i)
                bb[i] = *reinterpret_cast<const bf16x8*>(
                    &Bs[wn * 64 + i * 16 + l15][kk + lhi * 8]);
            #pragma unroll
            for (int mi = 0; mi < 4; ++mi)
                #pragma unroll
                for (int ni = 0; ni < 4; ++ni)
                    acc[mi][ni] = __builtin_amdgcn_mfma_f32_16x16x32_bf16(
                        af[mi], bb[ni], acc[mi][ni], 0, 0, 0);
        }
    }
    const int crow0 = m0 + wm * 64 + lhi * 4;
    const int ccol0 = bn * BN + wn * 64 + l15;
    #pragma unroll
    for (int mi = 0; mi < 4; ++mi)
        #pragma unroll
        for (int ni = 0; ni < 4; ++ni)
            #pragma unroll
            for (int r = 0; r < 4; ++r)
                out[(size_t)(crow0 + mi * 16 + r) * NTOT + ccol0 + ni * 16] =
                    acc[mi][ni][r];
}

extern "C" void kernel_launch(void* const* d_in, const int* in_sizes, int n_in,
                              void* d_out, int out_size, void* d_ws, size_t ws_size,
                              hipStream_t stream) {
    const float* x  = (const float*)d_in[0];
    const int*   qw = (const int*)d_in[1];
    const int*   qz = (const int*)d_in[2];
    const float* sc = (const float*)d_in[3];
    float*       out = (float*)d_out;

    const size_t xb_elems = (size_t)M * Dd;          // bf16
    const size_t wt_elems = (size_t)NTOT * Dd;       // bf16
    const size_t need = (xb_elems + wt_elems) * sizeof(short);  // ~201 MB

    if (ws_size >= need) {
        short* xb = (short*)d_ws;
        short* wt = xb + xb_elems;
        hipLaunchKernelGGL(xcvt, dim3(2048), dim3(256), 0, stream, x, xb);
        hipLaunchKernelGGL(wdq, dim3(Kk * (Dd / 64) * (Ff / 64)), dim3(256), 0, stream,
                           qw, qz, sc, wt);
        hipLaunchKernelGGL(gemm_bf16, dim3(NM * NN), dim3(256), 0, stream, xb, wt, out);
    } else {
        hipLaunchKernelGGL(int4_gemm, dim3(NM * NN), dim3(256), 0, stream,
                           x, qw, qz, sc, out);
    }
}

// Round 4
// 1151.634 us; speedup vs baseline: 2.6419x; 1.7146x over previous
//
#include <hip/hip_runtime.h>
#include <hip/hip_bf16.h>
#include <stdint.h>

// out[b,t,k,f] = sum_d x[b,t,d] * (qw[k,d,f]-qz[k,d/128,f])*sc[k,d/128,f]
// Stage 1: build swizzled bf16 panels in d_ws:
//   Xw: A panels [(m_half)*64 + kt] of 16KB: A[r][c] at byte (r*128+c*2)^((r&7)<<4)
//   Ww: B^T panels [(n_half)*64 + kt], same swizzle (r = n-row, c = d)
// Stage 2: 256x256x64 8-phase double-buffered MFMA GEMM (m201-style schedule).
// R4 fix: gemm256 grid was 16384 (operator-precedence bug) -> OOB reads/writes
// -> page-fault abort. Correct grid is NMB*NNB = 2048.

typedef __attribute__((ext_vector_type(8))) short bf16x8;
typedef __attribute__((ext_vector_type(4))) float f32x4;

static constexpr int Dd = 4096, Ff = 8192;
static constexpr int M = 8192, NTOT = 16384;
static constexpr int NKT = Dd / 64;       // 64 K-tiles
static constexpr int NMB = M / 256;       // 32
static constexpr int NNB = NTOT / 256;    // 64

__device__ __forceinline__ short f2bf(float f) {
    __hip_bfloat16 h = __float2bfloat16(f);
    return *reinterpret_cast<short*>(&h);
}

// ---------------- Stage 1a: x fp32 -> swizzled bf16 A-panels ----------------
__global__ __launch_bounds__(256) void xcvt(const float* __restrict__ x,
                                            char* __restrict__ Xw) {
    const int bid = blockIdx.x;             // h*64 + kt, h in [0,64)
    const int h = bid >> 6, kt = bid & 63;
    const int t = threadIdx.x;
    const int r = t >> 1, seg = t & 1;
    const float* src = x + ((size_t)(h * 128 + r)) * Dd + kt * 64 + seg * 32;
    char* panel = Xw + ((size_t)bid << 14);
    #pragma unroll
    for (int jj = 0; jj < 4; ++jj) {
        float4 v0 = *reinterpret_cast<const float4*>(src + jj * 8);
        float4 v1 = *reinterpret_cast<const float4*>(src + jj * 8 + 4);
        union { short s[8]; bf16x8 v; } u;
        u.s[0] = f2bf(v0.x); u.s[1] = f2bf(v0.y); u.s[2] = f2bf(v0.z); u.s[3] = f2bf(v0.w);
        u.s[4] = f2bf(v1.x); u.s[5] = f2bf(v1.y); u.s[6] = f2bf(v1.z); u.s[7] = f2bf(v1.w);
        const int cb = seg * 4 + jj;
        const int g = r * 8 + (cb ^ (r & 7));
        *reinterpret_cast<bf16x8*>(panel + g * 16) = u.v;
    }
}

// ---------------- Stage 1b: dequant int4 -> swizzled bf16 B^T panels ----------------
__global__ __launch_bounds__(256) void wdq(const int* __restrict__ qw,
                                           const int* __restrict__ qz,
                                           const float* __restrict__ sc,
                                           char* __restrict__ Ww) {
    const int bid = blockIdx.x;             // fh*64 + kt, fh in [0,128)
    const int fh = bid >> 6, kt = bid & 63;
    const int t = threadIdx.x;
    const int r = t & 127, dh = t >> 7;
    const int n = fh * 128 + r;
    const int k = n >> 13, f = n & 8191;
    const int g = kt >> 1;                  // 64-col tile within one 128-group
    const int   zv = qz[((size_t)k * 32 + g) * Ff + f];
    const float sv = sc[((size_t)k * 32 + g) * Ff + f];
    const int* qp = qw + ((size_t)(k * Dd + kt * 64 + dh * 32)) * Ff + f;
    char* panel = Ww + ((size_t)bid << 14);
    #pragma unroll
    for (int jj = 0; jj < 4; ++jj) {
        union { short s[8]; bf16x8 v; } u;
        #pragma unroll
        for (int e = 0; e < 8; ++e) {
            int q = qp[(size_t)(jj * 8 + e) * Ff];
            u.s[e] = f2bf((float)(q - zv) * sv);
        }
        const int cb = dh * 4 + jj;
        const int gi = r * 8 + (cb ^ (r & 7));
        *reinterpret_cast<bf16x8*>(panel + gi * 16) = u.v;
    }
}

// ---------------- Stage 2: 256x256 8-phase GEMM ----------------
#define APAN(HALF, KT) (Xw + (((size_t)(bm2 + (HALF)) * 64 + (KT)) << 14))
#define BPAN(HALF, KT) (Ww + (((size_t)(bn2 + (HALF)) * 64 + (KT)) << 14))

#define STAGE(GP, LP) do {                                                         \
    const char* _g = (GP) + woff16;                                                \
    char* _l = (LP) + woffu;                                                       \
    __builtin_amdgcn_global_load_lds(                                              \
        (const __attribute__((address_space(1))) void*)(_g),                       \
        (__attribute__((address_space(3))) void*)(_l), 16, 0, 0);                  \
    __builtin_amdgcn_global_load_lds(                                              \
        (const __attribute__((address_space(1))) void*)(_g + 8192),                \
        (__attribute__((address_space(3))) void*)(_l + 8192), 16, 0, 0);           \
} while (0)

// swizzled LDS read of one MFMA fragment (16B)
#define RDF(BASE, R, CB) \
    (*reinterpret_cast<const bf16x8*>((BASE) + ((((R) << 7) + (CB)) ^ (((R) & 7) << 4))))

#define PHASE(LA, LB, H, KK, LOADB, STG, WAITQ) do {                               \
    if (LOADB) {                                                                   \
        _Pragma("unroll")                                                          \
        for (int ni = 0; ni < 4; ++ni)                                             \
            bb[ni] = RDF((LB) + bpan, brow + ni * 16, (KK) * 2 + lhi16);           \
    }                                                                              \
    _Pragma("unroll")                                                              \
    for (int j = 0; j < 4; ++j)                                                    \
        af[j] = RDF((LA) + apan, ((H) * 4 + j) * 16 + l15, (KK) * 2 + lhi16);      \
    STG;                                                                           \
    __builtin_amdgcn_sched_barrier(0);                                             \
    __builtin_amdgcn_s_barrier();                                                  \
    asm volatile("s_waitcnt lgkmcnt(0)" ::: "memory");                             \
    __builtin_amdgcn_sched_barrier(0);                                             \
    __builtin_amdgcn_s_setprio(1);                                                 \
    _Pragma("unroll")                                                              \
    for (int j = 0; j < 4; ++j)                                                    \
        _Pragma("unroll")                                                          \
        for (int ni = 0; ni < 4; ++ni)                                             \
            acc[(H) * 4 + j][ni] = __builtin_amdgcn_mfma_f32_16x16x32_bf16(        \
                af[j], bb[ni], acc[(H) * 4 + j][ni], 0, 0, 0);                     \
    __builtin_amdgcn_s_setprio(0);                                                 \
    WAITQ;                                                                         \
    __builtin_amdgcn_sched_barrier(0);                                             \
    __builtin_amdgcn_s_barrier();                                                  \
} while (0)

__global__ __launch_bounds__(512, 2) void gemm256(const char* __restrict__ Xw,
                                                  const char* __restrict__ Ww,
                                                  float* __restrict__ out) {
    __shared__ char lds[131072];
    char* lA0 = lds;
    char* lB0 = lds + 32768;
    char* lA1 = lds + 65536;
    char* lB1 = lds + 98304;

    const int t = threadIdx.x;
    const int wave = t >> 6, lane = t & 63;
    const int wm = wave >> 2, wn = wave & 3;      // 2 x 4 waves
    const int l15 = lane & 15, lhi16 = (lane >> 4) * 16;

    // bijective XCD swizzle (2048 % 8 == 0); n-chunked so each XCD keeps a B slab L2-resident
    const int xcd = blockIdx.x & 7;
    const int c   = blockIdx.x >> 3;              // 0..255
    const int bn  = xcd * 8 + (c >> 5);           // 0..63
    const int bm  = c & 31;                       // 0..31
    const int bm2 = bm * 2, bn2 = bn * 2;

    const int woff16 = wave * 1024 + lane * 16;   // per-lane global offset
    const int woffu  = wave * 1024;               // wave-uniform LDS offset
    const int apan = wm * 16384;                  // wave's A half-panel
    const int bpan = (wn >> 1) * 16384;           // wave's B half-panel
    const int brow = (wn & 1) * 64 + l15;         // B row base within panel

    bf16x8 af[4], bb[4];
    f32x4 acc[8][4] = {};

    // prologue: tile0 (all 4 halves) + tile1.Bh0; wait tile0 landed
    STAGE(APAN(0, 0), lA0);
    STAGE(APAN(1, 0), lA0 + 16384);
    STAGE(BPAN(0, 0), lB0);
    STAGE(BPAN(1, 0), lB0 + 16384);
    STAGE(BPAN(0, 1), lB1);
    asm volatile("s_waitcnt vmcnt(2)" ::: "memory");
    __builtin_amdgcn_sched_barrier(0);
    __builtin_amdgcn_s_barrier();

    for (int i = 0; i < 32; ++i) {
        const int kt0 = 2 * i;
        const bool nl = (i < 31);
        // tile kt0 from buf0; stage rest of tile kt0+1 into buf1, then kt0+2 into buf0
        PHASE(lA0, lB0, 0, 0,  1, { STAGE(BPAN(1, kt0 + 1), lB1 + 16384); }, );
        PHASE(lA0, lB0, 1, 0,  0, { STAGE(APAN(0, kt0 + 1), lA1); }, );
        PHASE(lA0, lB0, 0, 32, 1, { STAGE(APAN(1, kt0 + 1), lA1 + 16384); }, );
        PHASE(lA0, lB0, 1, 32, 0, { if (nl) STAGE(BPAN(0, kt0 + 2), lB0); },
              { if (nl) asm volatile("s_waitcnt vmcnt(2)" ::: "memory");
                else    asm volatile("s_waitcnt vmcnt(0)" ::: "memory"); });
        // tile kt0+1 from buf1; stage kt0+2 rest into buf0, kt0+3.Bh0 into buf1
        PHASE(lA1, lB1, 0, 0,  1, { if (nl) STAGE(BPAN(1, kt0 + 2), lB0 + 16384); }, );
        PHASE(lA1, lB1, 1, 0,  0, { if (nl) STAGE(APAN(0, kt0 + 2), lA0); }, );
        PHASE(lA1, lB1, 0, 32, 1, { if (nl) STAGE(APAN(1, kt0 + 2), lA0 + 16384); }, );
        PHASE(lA1, lB1, 1, 32, 0, { if (nl) STAGE(BPAN(0, kt0 + 3), lB1); },
              { if (nl) asm volatile("s_waitcnt vmcnt(2)" ::: "memory");
                else    asm volatile("s_waitcnt vmcnt(0)" ::: "memory"); });
    }

    // epilogue: C/D layout col=lane&15, row=(lane>>4)*4+reg
    const int gr0 = bm * 256 + wm * 128 + (lhi16 >> 2);
    const int gc0 = bn * 256 + wn * 64 + l15;
    #pragma unroll
    for (int mi = 0; mi < 8; ++mi)
        #pragma unroll
        for (int ni = 0; ni < 4; ++ni)
            #pragma unroll
            for (int rr = 0; rr < 4; ++rr)
                out[(size_t)(gr0 + mi * 16 + rr) * NTOT + gc0 + ni * 16] =
                    acc[mi][ni][rr];
}

// ---------------- Fallback (ws too small): round-1 fused kernel ----------------
#define LDP 72
__global__ __launch_bounds__(256) void int4_gemm(
    const float* __restrict__ x, const int* __restrict__ qw,
    const int* __restrict__ qz, const float* __restrict__ sc,
    float* __restrict__ out)
{
    __shared__ short As[128][LDP];
    __shared__ short Bs[128][LDP];
    const int t = threadIdx.x;
    int gid = (blockIdx.x & 7) * 1024 + (blockIdx.x >> 3);
    const int bm = gid & 63;
    const int bnq = gid >> 6;
    const int kse = bnq >> 6;
    const int f0  = (bnq & 63) * 128;
    const int m0  = bm * 128;
    const int wave = t >> 6, lane = t & 63;
    const int wm = wave >> 1, wn = wave & 1;
    const int l15 = lane & 15, lhi = lane >> 4;
    const int am = t >> 4, ad = (t & 15) * 4;
    const int bf = t & 127, bd = (t >> 7) * 4;
    const int*   qwk = qw + (size_t)kse * Dd * Ff;
    const int*   qzk = qz + (size_t)kse * 32 * Ff;
    const float* sck = sc + (size_t)kse * 32 * Ff;
    f32x4 acc[4][4] = {};
    for (int d0 = 0; d0 < Dd; d0 += 64) {
        __syncthreads();
        #pragma unroll
        for (int p = 0; p < 8; ++p) {
            int m = p * 16 + am;
            const float4 v = *reinterpret_cast<const float4*>(
                &x[(size_t)(m0 + m) * Dd + d0 + ad]);
            short4 wv;
            wv.x = f2bf(v.x); wv.y = f2bf(v.y); wv.z = f2bf(v.z); wv.w = f2bf(v.w);
            *reinterpret_cast<short4*>(&As[m][ad]) = wv;
        }
        {
            const int g = d0 >> 7;
            const int   zv = qzk[g * Ff + f0 + bf];
            const float sv = sck[g * Ff + f0 + bf];
            #pragma unroll
            for (int p = 0; p < 8; ++p) {
                int dl = p * 8 + bd;
                const int* qp = qwk + (size_t)(d0 + dl) * Ff + f0 + bf;
                short4 wv;
                wv.x = f2bf((float)(qp[0]      - zv) * sv);
                wv.y = f2bf((float)(qp[Ff]     - zv) * sv);
                wv.z = f2bf((float)(qp[2 * Ff] - zv) * sv);
                wv.w = f2bf((float)(qp[3 * Ff] - zv) * sv);
                *reinterpret_cast<short4*>(&Bs[bf][dl]) = wv;
            }
        }
        __syncthreads();
        #pragma unroll
        for (int kk = 0; kk < 64; kk += 32) {
            bf16x8 a2[4], b2[4];
            #pragma unroll
            for (int i = 0; i < 4; ++i)
                a2[i] = *reinterpret_cast<const bf16x8*>(&As[wm * 64 + i * 16 + l15][kk + lhi * 8]);
            #pragma unroll
            for (int i = 0; i < 4; ++i)
                b2[i] = *reinterpret_cast<const bf16x8*>(&Bs[wn * 64 + i * 16 + l15][kk + lhi * 8]);
            #pragma unroll
            for (int mi = 0; mi < 4; ++mi)
                #pragma unroll
                for (int ni = 0; ni < 4; ++ni)
                    acc[mi][ni] = __builtin_amdgcn_mfma_f32_16x16x32_bf16(
                        a2[mi], b2[ni], acc[mi][ni], 0, 0, 0);
        }
    }
    const int crow0 = m0 + wm * 64 + lhi * 4;
    const int ccol0 = bnq * 128 + wn * 64 + l15;
    #pragma unroll
    for (int mi = 0; mi < 4; ++mi)
        #pragma unroll
        for (int ni = 0; ni < 4; ++ni)
            #pragma unroll
            for (int r = 0; r < 4; ++r)
                out[(size_t)(crow0 + mi * 16 + r) * NTOT + ccol0 + ni * 16] =
                    acc[mi][ni][r];
}

extern "C" void kernel_launch(void* const* d_in, const int* in_sizes, int n_in,
                              void* d_out, int out_size, void* d_ws, size_t ws_size,
                              hipStream_t stream) {
    const float* x  = (const float*)d_in[0];
    const int*   qw = (const int*)d_in[1];
    const int*   qz = (const int*)d_in[2];
    const float* sc = (const float*)d_in[3];
    float*       out = (float*)d_out;

    const size_t xw_bytes = (size_t)(M / 128) * NKT * 16384;      // 64 MiB
    const size_t ww_bytes = (size_t)(NTOT / 128) * NKT * 16384;   // 128 MiB

    if (ws_size >= xw_bytes + ww_bytes) {
        char* Xw = (char*)d_ws;
        char* Ww = Xw + xw_bytes;
        hipLaunchKernelGGL(xcvt, dim3((M / 128) * NKT), dim3(256), 0, stream, x, Xw);
        hipLaunchKernelGGL(wdq, dim3((NTOT / 128) * NKT), dim3(256), 0, stream,
                           qw, qz, sc, Ww);
        hipLaunchKernelGGL(gemm256, dim3(NMB * NNB), dim3(512), 0, stream,
                           Xw, Ww, out);
    } else {
        hipLaunchKernelGGL(int4_gemm, dim3(8192), dim3(256), 0, stream,
                           x, qw, qz, sc, out);
    }
}